// Round 9
// baseline (148.362 us; speedup 1.0000x reference)
//
#include <hip/hip_runtime.h>
#include <math.h>

// Problem constants (from reference): B=64, T=2048, D=256
#define BB 64
#define TT 2048
#define D4 64             // D/4 -> one float4 per lane, one wave covers D
#define SS 64             // time segments
#define LL (TT / SS)      // 32 steps per segment
#define WPB 4             // waves per block (each wave owns one chain b)
#define BPG (BB / WPB)    // 16 b-groups
#define GRID (SS * BPG)   // 1024 blocks, s-major
#define SEG ((size_t)SS * BB * D4)   // f4 elements per partials buffer
#define CANARY 0x7FC0DEADu           // quiet-NaN payload; real data never equals it

typedef float f4 __attribute__((ext_vector_type(4)));

// -------------------- math helpers --------------------

__device__ __forceinline__ float softplus_f(float x) {
    return (x > 0.f) ? (x + log1pf(expf(-x))) : log1pf(expf(x));
}

struct P4 { f4 k, s2, r, mu; };
struct C4 { f4 A, bm, sQ; };
struct P1 { float k, s2, r; };
struct C1 { float A, bm, sQ; };

__device__ __forceinline__ P1 sp1(float lk, float ls) {
    P1 o;
    o.k = softplus_f(lk) + 1e-6f;
    float s = softplus_f(ls) + 1e-6f;
    o.s2 = s * s;
    o.r = o.s2 / fmaxf(2.f * o.k, 1e-12f);
    return o;
}

__device__ __forceinline__ P4 load_params4(const f4* __restrict__ mu4,
                                           const f4* __restrict__ lk4,
                                           const f4* __restrict__ ls4,
                                           int lane) {
    f4 lk = lk4[lane], ls = ls4[lane], mu = mu4[lane];
    P4 p;
    P1 a;
    a = sp1(lk.x, ls.x); p.k.x = a.k; p.s2.x = a.s2; p.r.x = a.r;
    a = sp1(lk.y, ls.y); p.k.y = a.k; p.s2.y = a.s2; p.r.y = a.r;
    a = sp1(lk.z, ls.z); p.k.z = a.k; p.s2.z = a.s2; p.r.z = a.r;
    a = sp1(lk.w, ls.w); p.k.w = a.k; p.s2.w = a.s2; p.r.w = a.r;
    p.mu = mu;
    return p;
}

__device__ __forceinline__ C1 ou_coeff(float dt, float kappa, float s2, float r,
                                       float mu) {
    C1 o;
    float e = kappa * dt;
    o.A = __expf(-e);
    float two = 2.f * e;
    float Qe = r * (1.f - o.A * o.A);
    float Qt = s2 * dt * fmaf(two * two, (1.f / 6.f), 1.f - e);
    float Q = (two < 1e-6f) ? Qt : Qe;
    o.sQ = sqrtf(Q);
    o.bm = mu * (1.f - o.A);
    return o;
}

__device__ __forceinline__ C4 coeff4(float dt, const P4& p) {
    C4 c;
    C1 o;
    o = ou_coeff(dt, p.k.x, p.s2.x, p.r.x, p.mu.x); c.A.x = o.A; c.bm.x = o.bm; c.sQ.x = o.sQ;
    o = ou_coeff(dt, p.k.y, p.s2.y, p.r.y, p.mu.y); c.A.y = o.A; c.bm.y = o.bm; c.sQ.y = o.sQ;
    o = ou_coeff(dt, p.k.z, p.s2.z, p.r.z, p.mu.z); c.A.z = o.A; c.bm.z = o.bm; c.sQ.z = o.sQ;
    o = ou_coeff(dt, p.k.w, p.s2.w, p.r.w, p.mu.w); c.A.w = o.A; c.bm.w = o.bm; c.sQ.w = o.sQ;
    return c;
}

__device__ __forceinline__ f4 sqrt4(const f4 v) {
    f4 r;
    r.x = sqrtf(v.x); r.y = sqrtf(v.y); r.z = sqrtf(v.z); r.w = sqrtf(v.w);
    return r;
}

__device__ __forceinline__ bool any_canary(f4 v) {
    return (__float_as_uint(v.x) == CANARY) || (__float_as_uint(v.y) == CANARY) ||
           (__float_as_uint(v.z) == CANARY) || (__float_as_uint(v.w) == CANARY);
}

// Cold path: recompute segment j's (P,U) directly from noise. Keeps
// correctness independent of XCD mapping, dispatch order, cache behavior.
__device__ void recompute_seg(int j, const f4* __restrict__ np,
                              const float* __restrict__ ts, const P4& p,
                              f4* Pj, f4* Uj) {
    f4 U = {0.f, 0.f, 0.f, 0.f};
    f4 P = {1.f, 1.f, 1.f, 1.f};
    float dtprev = -1.f;
    C4 cc;
    const int t0 = j * LL;
    for (int i = 0; i < LL; ++i) {
        int t = t0 + i;
        float dt = 1e-6f;
        if (t >= 1) dt = fmaxf(ts[t] - ts[t - 1], 1e-6f);
        f4 n = __builtin_nontemporal_load(np + (size_t)t * D4);
        if (dt != dtprev) { cc = coeff4(dt, p); dtprev = dt; }
        f4 cv = cc.sQ * n + cc.bm;
        f4 a = cc.A;
        if (j == 0 && i == 0) {
            cv = n * sqrt4(p.r) + p.mu;
            a = (f4){0.f, 0.f, 0.f, 0.f};
        }
        U = a * U + cv;
        P = P * a;
    }
    *Pj = P;
    *Uj = U;
}

// -------------------- init: canary-fill the partials buffers ---------------
// Runs as its own dispatch; kernel completion makes the canary globally
// visible (end-of-kernel writeback), so the main kernel's sc0/MALL reads can
// never observe harness poison as "valid data".
__global__ __launch_bounds__(256) void ou_init(f4* __restrict__ Pw,
                                               f4* __restrict__ Uw) {
    size_t i = (size_t)blockIdx.x * 256 + threadIdx.x;   // grid covers SEG exactly
    f4 c;
    c.x = c.y = c.z = c.w = __uint_as_float(CANARY);
    Pw[i] = c;
    Uw[i] = c;
}

// ==================== single-dispatch fence-free scan ====================
// Block (s,bg): 4 waves, wave w owns chain b = bg*4+w. Phase A: NT-read this
// segment's noise ONCE, build (P,U), keep innovations c[i] in registers,
// publish (P,U) with PLAIN stores (write-through L1 -> home-XCD L2).
// Phase B: for j=0..s-1, volatile(sc0) load predecessor (P,U); canary ->
// sleep-retry; timeout -> recompute from noise (cold). No fences, no
// atomics, no flags: data-is-the-flag. Then replay from registers and
// NT-store the output. Segment-0 partial has P=0 (absorbing), so the scan
// is uniformly inc = P_j*inc + U_j from inc=0.
__global__ __launch_bounds__(256, 2) void ou_onepass(
    const float* __restrict__ ts, const f4* __restrict__ noise4,
    const f4* __restrict__ mu4, const f4* __restrict__ lk4,
    const f4* __restrict__ ls4,
    f4* __restrict__ Pw, f4* __restrict__ Uw, f4* __restrict__ out4) {
    __shared__ float dts[LL];
    const int lane = threadIdx.x & 63;
    const int w = threadIdx.x >> 6;
    const int s = blockIdx.x / BPG;     // s-major: low s dispatched first
    const int bg = blockIdx.x % BPG;    // blockIdx%8 = bg%8 -> column XCD-affinity
    const int b = bg * WPB + w;
    const int t0 = s * LL;

    if (threadIdx.x < LL) {
        int k = t0 + threadIdx.x;
        float dt = 1e-6f;
        if (k >= 1) dt = fmaxf(ts[k] - ts[k - 1], 1e-6f);
        dts[threadIdx.x] = dt;
    }
    __syncthreads();

    P4 p = load_params4(mu4, lk4, ls4, lane);
    const f4* np = noise4 + (size_t)b * TT * D4 + lane;

    // ---------------- phase A: partials + c[] in registers ----------------
    f4 c[LL];
    f4 U = {0.f, 0.f, 0.f, 0.f};
    f4 P = {1.f, 1.f, 1.f, 1.f};
    float dtprev = -1.f;
    C4 cc;
#pragma unroll
    for (int i = 0; i < LL; ++i) {
        float dt = dts[i];
        f4 n = __builtin_nontemporal_load(np + (size_t)(t0 + i) * D4);
        if (dt != dtprev) { cc = coeff4(dt, p); dtprev = dt; } // wave-uniform
        f4 cv = cc.sQ * n + cc.bm;
        f4 a = cc.A;
        if (s == 0 && i == 0) {            // fold initial condition
            cv = n * sqrt4(p.r) + p.mu;
            a = (f4){0.f, 0.f, 0.f, 0.f};  // absorbing
        }
        c[i] = cv;
        U = a * U + cv;
        P = P * a;
    }

    // publish with plain stores (stay in home-XCD L2; NT noise loads kept it clean)
    {
        size_t idx = ((size_t)s * BB + b) * D4 + lane;
        Pw[idx] = P;
        Uw[idx] = U;
    }

    // ---------------- phase B: poll-scan predecessors ----------------
    f4 y = {0.f, 0.f, 0.f, 0.f};
    if (s > 0) {
        f4 inc = {0.f, 0.f, 0.f, 0.f};
        for (int j = 0; j < s; ++j) {
            size_t idx = ((size_t)j * BB + b) * D4 + lane;
            f4 Pj, Uj;
            int tries = 0;
            bool good = false;
            for (;;) {
                Pj = *(volatile const f4*)(Pw + idx);   // sc0: bypass L1, read L2
                Uj = *(volatile const f4*)(Uw + idx);
                bool bad = any_canary(Pj) || any_canary(Uj);
                if (!__any(bad)) { good = true; break; }
                if (++tries > 1500) break;              // ~0.3 ms cap
                __builtin_amdgcn_s_sleep(8);            // ~512 cy backoff
            }
            if (!good) recompute_seg(j, np, ts, p, &Pj, &Uj);
            inc = Pj * inc + Uj;
        }
        y = inc;    // true state at end of segment s-1
    }

    // ---------------- replay from registers, NT-store output ----------------
    f4* op = out4 + (size_t)b * TT * D4 + lane;
    const f4 kap = p.k;
    dtprev = -1.f;
    f4 A;
#pragma unroll 4
    for (int i = 0; i < LL; ++i) {
        float dt = dts[i];
        if (dt != dtprev) {
            A.x = __expf(-kap.x * dt);
            A.y = __expf(-kap.y * dt);
            A.z = __expf(-kap.z * dt);
            A.w = __expf(-kap.w * dt);
            dtprev = dt;
        }
        f4 a = A;
        if (s == 0 && i == 0) a = (f4){0.f, 0.f, 0.f, 0.f};
        y = a * y + c[i];
        __builtin_nontemporal_store(y, op + (size_t)(t0 + i) * D4);
    }
}

// -------------------- last-resort fallback: plain per-chain scan ------------
__global__ __launch_bounds__(128) void ou_fallback(
    const float* __restrict__ ts, const float2* __restrict__ noise2,
    const float2* __restrict__ mu2, const float2* __restrict__ lk2,
    const float2* __restrict__ ls2, float2* __restrict__ out2) {
    __shared__ float dts[TT];
    const int tid = threadIdx.x;
    const int b = blockIdx.x;
    for (int i = tid; i < TT; i += 128) {
        float dt = 1e-6f;
        if (i >= 1) dt = fmaxf(ts[i] - ts[i - 1], 1e-6f);
        dts[i] = dt;
    }
    __syncthreads();

    float2 lk = lk2[tid], ls = ls2[tid], mu = mu2[tid];
    P1 px = sp1(lk.x, ls.x);
    P1 py = sp1(lk.y, ls.y);

    const float2* np = noise2 + (size_t)b * TT * 128 + tid;
    float2* op = out2 + (size_t)b * TT * 128 + tid;

    float2 n0 = np[0];
    float2 y;
    y.x = fmaf(n0.x, sqrtf(px.r), mu.x);
    y.y = fmaf(n0.y, sqrtf(py.r), mu.y);
    op[0] = y;

#pragma unroll 4
    for (int k = 1; k < TT; ++k) {
        float dt = dts[k];
        float2 n = np[(size_t)k * 128];
        C1 cx = ou_coeff(dt, px.k, px.s2, px.r, mu.x);
        C1 cy = ou_coeff(dt, py.k, py.s2, py.r, mu.y);
        y.x = fmaf(cx.A, y.x, fmaf(cx.sQ, n.x, cx.bm));
        y.y = fmaf(cy.A, y.y, fmaf(cy.sQ, n.y, cy.bm));
        op[(size_t)k * 128] = y;
    }
}

// -------------------- launch --------------------
extern "C" void kernel_launch(void* const* d_in, const int* in_sizes, int n_in,
                              void* d_out, int out_size, void* d_ws, size_t ws_size,
                              hipStream_t stream) {
    const float* ts = (const float*)d_in[0];
    const f4* noise4 = (const f4*)d_in[1];
    const f4* mu4 = (const f4*)d_in[2];
    const f4* lk4 = (const f4*)d_in[3];
    const f4* ls4 = (const f4*)d_in[4];
    f4* out4 = (f4*)d_out;

    if (ws_size >= 2 * SEG * sizeof(f4)) {
        f4* Pw = (f4*)d_ws;
        f4* Uw = Pw + SEG;
        ou_init<<<(int)(SEG / 256), 256, 0, stream>>>(Pw, Uw);
        ou_onepass<<<GRID, 256, 0, stream>>>(ts, noise4, mu4, lk4, ls4,
                                             Pw, Uw, out4);
    } else {
        ou_fallback<<<BB, 128, 0, stream>>>(ts, (const float2*)d_in[1],
                                            (const float2*)d_in[2],
                                            (const float2*)d_in[3],
                                            (const float2*)d_in[4],
                                            (float2*)d_out);
    }
}

// Round 10
// 134.581 us; speedup vs baseline: 1.1024x; 1.1024x over previous
//
#include <hip/hip_runtime.h>
#include <math.h>

// Problem constants (from reference): B=64, T=2048, D=256
#define BB 64
#define TT 2048
#define SS 64              // time segments
#define LL (TT / SS)       // 32 steps per segment
#define NCOL 128           // columns = chain * dim-half (b*2 + half)
#define BPG 32             // b-groups per segment (2 chains per block)
#define GRID (SS * BPG)    // 2048 blocks, s-major; blockIdx%8 == bg%8 -> XCD-affine
#define NSLOT ((size_t)SS * NCOL * 64)   // f4 slots in the PU buffer (8.4 MB)
#define CANARY 0x7FC0DEADu // quiet-NaN payload; finite data never equals it

typedef float f2 __attribute__((ext_vector_type(2)));
typedef float f4 __attribute__((ext_vector_type(4)));

// -------------------- math helpers --------------------

__device__ __forceinline__ float softplus_f(float x) {
    return (x > 0.f) ? (x + log1pf(expf(-x))) : log1pf(expf(x));
}

struct P2 { f2 k, s2, r, mu; };   // per-lane params for 2 chains (f2)
struct C2 { f2 A, bm, sQ; };      // per-step coefficients
struct P1 { float k, s2, r; };
struct C1 { float A, bm, sQ; };

__device__ __forceinline__ P1 sp1(float lk, float ls) {
    P1 o;
    o.k = softplus_f(lk) + 1e-6f;
    float s = softplus_f(ls) + 1e-6f;
    o.s2 = s * s;
    o.r = o.s2 / fmaxf(2.f * o.k, 1e-12f);
    return o;
}

__device__ __forceinline__ C1 ou_coeff(float dt, float kappa, float s2, float r,
                                       float mu) {
    C1 o;
    float e = kappa * dt;
    o.A = __expf(-e);
    float two = 2.f * e;
    float Qe = r * (1.f - o.A * o.A);
    float Qt = s2 * dt * fmaf(two * two, (1.f / 6.f), 1.f - e);
    float Q = (two < 1e-6f) ? Qt : Qe;
    o.sQ = sqrtf(Q);
    o.bm = mu * (1.f - o.A);
    return o;
}

__device__ __forceinline__ C2 coeff2(float dt, const P2& p) {
    C2 c;
    C1 o;
    o = ou_coeff(dt, p.k.x, p.s2.x, p.r.x, p.mu.x); c.A.x = o.A; c.bm.x = o.bm; c.sQ.x = o.sQ;
    o = ou_coeff(dt, p.k.y, p.s2.y, p.r.y, p.mu.y); c.A.y = o.A; c.bm.y = o.bm; c.sQ.y = o.sQ;
    return c;
}

__device__ __forceinline__ f2 sqrt2(const f2 v) {
    f2 r;
    r.x = sqrtf(v.x); r.y = sqrtf(v.y);
    return r;
}

__device__ __forceinline__ bool any_canary4(f4 v) {
    return (__float_as_uint(v.x) == CANARY) || (__float_as_uint(v.y) == CANARY) ||
           (__float_as_uint(v.z) == CANARY) || (__float_as_uint(v.w) == CANARY);
}

// Cold path: recompute segment j's (P,U) for this wave's 128-dim half-chain
// directly from noise. Correctness never depends on timing/XCD mapping.
__device__ void recompute_seg(int j, const f2* __restrict__ np,
                              const float* __restrict__ ts, const P2& p,
                              bool fold_ic, f2* Pj, f2* Uj) {
    f2 U = {0.f, 0.f};
    f2 P = {1.f, 1.f};
    float dtprev = -1.f;
    C2 cc;
    const int t0 = j * LL;
    for (int i = 0; i < LL; ++i) {
        int t = t0 + i;
        float dt = 1e-6f;
        if (t >= 1) dt = fmaxf(ts[t] - ts[t - 1], 1e-6f);
        f2 n = __builtin_nontemporal_load(np + (size_t)t * NCOL);
        if (dt != dtprev) { cc = coeff2(dt, p); dtprev = dt; }
        f2 cv = cc.sQ * n + cc.bm;
        f2 a = cc.A;
        if (fold_ic && j == 0 && i == 0) {
            cv = n * sqrt2(p.r) + p.mu;
            a = (f2){0.f, 0.f};
        }
        U = a * U + cv;
        P = P * a;
    }
    *Pj = P;
    *Uj = U;
}

// -------------------- init: canary-fill the PU buffer ---------------------
__global__ __launch_bounds__(256) void ou_init(f4* __restrict__ PU) {
    size_t i = (size_t)blockIdx.x * 256 + threadIdx.x;   // grid covers NSLOT
    f4 c;
    c.x = c.y = c.z = c.w = __uint_as_float(CANARY);
    PU[i] = c;
}

// ==================== single-dispatch fence-free scan (spill-free) =========
// Block (s,bg): 4 waves; wave w owns column col = bg*4+w (chain b = col>>1,
// dim-half = col&1, 128 dims as f2/lane). Phase A: NT-read noise ONCE, build
// (P,U), keep innovations c[i] (64 VGPRs) in registers, publish packed
// (P,U) f4 with a PLAIN store (write-through to home-XCD L2; all blocks of
// a column share that XCD since blockIdx%8 = bg%8). Phase B: volatile-load
// predecessors' PU; canary -> sleep-retry; timeout -> recompute from noise.
// Then replay from registers, NT-store output. No fences, no atomics.
__global__ __launch_bounds__(256, 3) void ou_onepass(
    const float* __restrict__ ts, const f2* __restrict__ noise2,
    const f2* __restrict__ mu2, const f2* __restrict__ lk2,
    const f2* __restrict__ ls2,
    f4* __restrict__ PU, f2* __restrict__ out2) {
    __shared__ float dts[LL];
    const int lane = threadIdx.x & 63;
    const int w = threadIdx.x >> 6;
    const int s = blockIdx.x / BPG;     // s-major: low s dispatched first
    const int bg = blockIdx.x % BPG;
    const int col = bg * 4 + w;         // 0..127
    const int b = col >> 1;
    const int half = col & 1;
    const int t0 = s * LL;

    if (threadIdx.x < LL) {
        int k = t0 + threadIdx.x;
        float dt = 1e-6f;
        if (k >= 1) dt = fmaxf(ts[k] - ts[k - 1], 1e-6f);
        dts[threadIdx.x] = dt;
    }
    __syncthreads();

    // per-lane params for this wave's 2 dims (dim index = half*128 + lane*2)
    const int d2 = half * 64 + lane;    // float2 index into D/2 = 128
    P2 p;
    {
        f2 lk = lk2[d2], ls = ls2[d2], mu = mu2[d2];
        P1 a;
        a = sp1(lk.x, ls.x); p.k.x = a.k; p.s2.x = a.s2; p.r.x = a.r;
        a = sp1(lk.y, ls.y); p.k.y = a.k; p.s2.y = a.s2; p.r.y = a.r;
        p.mu = mu;
    }

    const f2* np = noise2 + (size_t)b * TT * NCOL + d2;

    // ---------------- phase A: partials + c[] in registers (no spill) ------
    f2 c[LL];
    f2 U = {0.f, 0.f};
    f2 P = {1.f, 1.f};
    float dtprev = -1.f;
    C2 cc;
#pragma unroll
    for (int i = 0; i < LL; ++i) {
        float dt = dts[i];
        f2 n = __builtin_nontemporal_load(np + (size_t)(t0 + i) * NCOL);
        if (dt != dtprev) { cc = coeff2(dt, p); dtprev = dt; } // wave-uniform
        f2 cv = cc.sQ * n + cc.bm;
        f2 a = cc.A;
        if (s == 0 && i == 0) {            // fold initial condition
            cv = n * sqrt2(p.r) + p.mu;
            a = (f2){0.f, 0.f};            // absorbing
        }
        c[i] = cv;
        U = a * U + cv;
        P = P * a;
    }

    // publish packed (P,U) with a plain store -> home-XCD L2
    {
        size_t idx = ((size_t)s * NCOL + col) * 64 + lane;
        f4 pu;
        pu.x = P.x; pu.y = P.y; pu.z = U.x; pu.w = U.y;
        PU[idx] = pu;
    }

    // ---------------- phase B: poll-scan predecessors ----------------
    f2 y = {0.f, 0.f};
    if (s > 0) {
        f2 inc = {0.f, 0.f};
        for (int j = 0; j < s; ++j) {
            size_t idx = ((size_t)j * NCOL + col) * 64 + lane;
            f2 Pj, Uj;
            int tries = 0;
            bool good = false;
            for (;;) {
                f4 v = *(volatile const f4*)(PU + idx);  // bypass L1, read L2
                if (!__any(any_canary4(v))) {
                    Pj.x = v.x; Pj.y = v.y;
                    Uj.x = v.z; Uj.y = v.w;
                    good = true;
                    break;
                }
                if (++tries > 2000) break;               // ~0.4 ms cap
                __builtin_amdgcn_s_sleep(8);             // ~512 cy backoff
            }
            if (!good) recompute_seg(j, np, ts, p, true, &Pj, &Uj);
            inc = Pj * inc + Uj;
        }
        y = inc;    // true state at end of segment s-1
    }

    // ---------------- replay from registers, NT-store output ----------------
    f2* op = out2 + (size_t)b * TT * NCOL + d2;
    dtprev = -1.f;
    f2 A;
#pragma unroll 4
    for (int i = 0; i < LL; ++i) {
        float dt = dts[i];
        if (dt != dtprev) {
            A.x = __expf(-p.k.x * dt);
            A.y = __expf(-p.k.y * dt);
            dtprev = dt;
        }
        f2 a = A;
        if (s == 0 && i == 0) a = (f2){0.f, 0.f};
        y = a * y + c[i];
        __builtin_nontemporal_store(y, op + (size_t)(t0 + i) * NCOL);
    }
}

// -------------------- last-resort fallback: plain per-chain scan ------------
__global__ __launch_bounds__(128) void ou_fallback(
    const float* __restrict__ ts, const float2* __restrict__ noise2,
    const float2* __restrict__ mu2, const float2* __restrict__ lk2,
    const float2* __restrict__ ls2, float2* __restrict__ out2) {
    __shared__ float dts[TT];
    const int tid = threadIdx.x;
    const int b = blockIdx.x;
    for (int i = tid; i < TT; i += 128) {
        float dt = 1e-6f;
        if (i >= 1) dt = fmaxf(ts[i] - ts[i - 1], 1e-6f);
        dts[i] = dt;
    }
    __syncthreads();

    float2 lk = lk2[tid], ls = ls2[tid], mu = mu2[tid];
    P1 px = sp1(lk.x, ls.x);
    P1 py = sp1(lk.y, ls.y);

    const float2* np = noise2 + (size_t)b * TT * 128 + tid;
    float2* op = out2 + (size_t)b * TT * 128 + tid;

    float2 n0 = np[0];
    float2 y;
    y.x = fmaf(n0.x, sqrtf(px.r), mu.x);
    y.y = fmaf(n0.y, sqrtf(py.r), mu.y);
    op[0] = y;

#pragma unroll 4
    for (int k = 1; k < TT; ++k) {
        float dt = dts[k];
        float2 n = np[(size_t)k * 128];
        C1 cx = ou_coeff(dt, px.k, px.s2, px.r, mu.x);
        C1 cy = ou_coeff(dt, py.k, py.s2, py.r, mu.y);
        y.x = fmaf(cx.A, y.x, fmaf(cx.sQ, n.x, cx.bm));
        y.y = fmaf(cy.A, y.y, fmaf(cy.sQ, n.y, cy.bm));
        op[(size_t)k * 128] = y;
    }
}

// -------------------- launch --------------------
extern "C" void kernel_launch(void* const* d_in, const int* in_sizes, int n_in,
                              void* d_out, int out_size, void* d_ws, size_t ws_size,
                              hipStream_t stream) {
    const float* ts = (const float*)d_in[0];

    if (ws_size >= NSLOT * sizeof(f4)) {
        f4* PU = (f4*)d_ws;
        ou_init<<<(int)(NSLOT / 256), 256, 0, stream>>>(PU);
        ou_onepass<<<GRID, 256, 0, stream>>>(ts, (const f2*)d_in[1],
                                             (const f2*)d_in[2],
                                             (const f2*)d_in[3],
                                             (const f2*)d_in[4],
                                             PU, (f2*)d_out);
    } else {
        ou_fallback<<<BB, 128, 0, stream>>>(ts, (const float2*)d_in[1],
                                            (const float2*)d_in[2],
                                            (const float2*)d_in[3],
                                            (const float2*)d_in[4],
                                            (float2*)d_out);
    }
}